// Round 1
// baseline (626.820 us; speedup 1.0000x reference)
//
#include <hip/hip_runtime.h>
#include <hip/hip_bf16.h>
#include <stdint.h>

// NGCF forward, node-factored form:
//   s1[i]   = sum_{e: col=i} norm_e * x[row_e]
//   aggr[i] = W1 s1[i] + W2 (x[i] .* s1[i]) + c[i]*(b1+b2),  c[i] = sum norm_e
//   x_next  = leaky_relu(aggr, 0.01)
// Layers' outputs are written straight into their column block of out[N,256].

__global__ void k_count(const int* __restrict__ col, int E, unsigned int* __restrict__ deg) {
  int e = blockIdx.x * blockDim.x + threadIdx.x;
  if (e < E) atomicAdd(&deg[col[e]], 1u);
}

__global__ void k_dis(const unsigned int* __restrict__ deg, float* __restrict__ dis, int N) {
  int i = blockIdx.x * blockDim.x + threadIdx.x;
  if (i < N) {
    unsigned int d = deg[i];
    dis[i] = d ? rsqrtf((float)d) : 0.0f;
  }
}

// Hillis-Steele inclusive scan per 1024-block
__global__ void k_scan1(const unsigned int* __restrict__ deg, unsigned int* __restrict__ incl,
                        unsigned int* __restrict__ bsum, int N) {
  __shared__ unsigned int sm[1024];
  int t = threadIdx.x;
  int i = blockIdx.x * 1024 + t;
  unsigned int v = (i < N) ? deg[i] : 0u;
  sm[t] = v;
  __syncthreads();
  for (int off = 1; off < 1024; off <<= 1) {
    unsigned int u = (t >= off) ? sm[t - off] : 0u;
    __syncthreads();
    sm[t] += u;
    __syncthreads();
  }
  if (i < N) incl[i] = sm[t];
  if (t == 1023) bsum[blockIdx.x] = sm[1023];
}

__global__ void k_scan2(const unsigned int* __restrict__ bsum, unsigned int* __restrict__ boff, int nblk) {
  if (blockIdx.x == 0 && threadIdx.x == 0) {
    unsigned int a = 0;
    for (int i = 0; i < nblk; ++i) { boff[i] = a; a += bsum[i]; }
  }
}

__global__ void k_scan3(const unsigned int* __restrict__ deg, const unsigned int* __restrict__ incl,
                        const unsigned int* __restrict__ boff, unsigned int* __restrict__ rowptr,
                        unsigned int* __restrict__ cursor, int N, int E) {
  int i = blockIdx.x * blockDim.x + threadIdx.x;
  if (i < N) {
    unsigned int ex = incl[i] - deg[i] + boff[i >> 10];
    rowptr[i] = ex;
    cursor[i] = ex;
  }
  if (i == 0) rowptr[N] = (unsigned int)E;
}

__global__ void k_fill(const int* __restrict__ row, const int* __restrict__ col, int E,
                       const float* __restrict__ dis, unsigned int* __restrict__ cursor,
                       int* __restrict__ csr_src, float* __restrict__ csr_w) {
  int e = blockIdx.x * blockDim.x + threadIdx.x;
  if (e < E) {
    int r = row[e];
    int c = col[e];
    unsigned int pos = atomicAdd(&cursor[c], 1u);
    csr_src[pos] = r;
    csr_w[pos] = dis[r] * dis[c];
  }
}

// x0 = concat(user_emb, item_emb) -> out columns [0,64)
__global__ void k_init(const float* __restrict__ ue, const float* __restrict__ ie,
                       float* __restrict__ out, int Nu, int Ntot) {
  int idx = blockIdx.x * blockDim.x + threadIdx.x;
  if (idx >= Ntot * 64) return;
  int n = idx >> 6;
  int f = idx & 63;
  float v = (n < Nu) ? ue[idx] : ie[idx - Nu * 64];
  out[(size_t)n * 256 + f] = v;
}

// one wave per node; lane f accumulates feature f of s1
__global__ __launch_bounds__(256) void k_aggregate(
    const unsigned int* __restrict__ rowptr, const int* __restrict__ csr_src,
    const float* __restrict__ csr_w, const float* __restrict__ out,
    float* __restrict__ S1, float* __restrict__ cvec, int N, int pcol)
{
  int lane = threadIdx.x & 63;
  int wglobal = (blockIdx.x * (int)blockDim.x + (int)threadIdx.x) >> 6;
  int nwaves = (int)((gridDim.x * blockDim.x) >> 6);
  for (int n0 = wglobal; n0 < N; n0 += nwaves) {
    int n = __builtin_amdgcn_readfirstlane(n0);
    unsigned int beg = rowptr[n];
    unsigned int end = rowptr[n + 1];
    float s1 = 0.0f, c = 0.0f;
    for (unsigned int e = beg; e < end; ++e) {
      int src = csr_src[e];
      float w = csr_w[e];
      s1 = fmaf(w, out[(size_t)src * 256 + pcol + lane], s1);
      c += w;
    }
    S1[(size_t)n * 64 + lane] = s1;
    if (lane == 0) cvec[n] = c;
  }
}

// one wave per node; lane o holds rows W1[o][:], W2[o][:] in registers,
// s1/x broadcast via uniform (scalar) loads.
__global__ __launch_bounds__(256) void k_transform(
    const float* __restrict__ S1, const float* __restrict__ cvec,
    float* __restrict__ out,
    const float* __restrict__ W1, const float* __restrict__ b1,
    const float* __restrict__ W2, const float* __restrict__ b2,
    int N, int pcol, int lcol)
{
  int lane = threadIdx.x & 63;
  float w1r[64], w2r[64];
#pragma unroll
  for (int f = 0; f < 64; ++f) {
    w1r[f] = W1[lane * 64 + f];
    w2r[f] = W2[lane * 64 + f];
  }
  float bb = b1[lane] + b2[lane];
  int wglobal = (blockIdx.x * (int)blockDim.x + (int)threadIdx.x) >> 6;
  int nwaves = (int)((gridDim.x * blockDim.x) >> 6);
  for (int n0 = wglobal; n0 < N; n0 += nwaves) {
    int n = __builtin_amdgcn_readfirstlane(n0);
    const float* s1p = S1 + (size_t)n * 64;
    const float* xp = out + (size_t)n * 256 + pcol;
    float acc = cvec[n] * bb;
#pragma unroll
    for (int f = 0; f < 64; ++f) {
      float s1f = s1p[f];
      float xf = xp[f];
      acc = fmaf(s1f, w1r[f], acc);
      acc = fmaf(xf * s1f, w2r[f], acc);
    }
    float r = (acc > 0.0f) ? acc : 0.01f * acc;
    out[(size_t)n * 256 + lcol + lane] = r;
  }
}

extern "C" void kernel_launch(void* const* d_in, const int* in_sizes, int n_in,
                              void* d_out, int out_size, void* d_ws, size_t ws_size,
                              hipStream_t stream) {
  const int* eidx = (const int*)d_in[0];
  const float* ue = (const float*)d_in[1];
  const float* ie = (const float*)d_in[2];
  const float* W1 = (const float*)d_in[3];
  const float* b1 = (const float*)d_in[4];
  const float* W2 = (const float*)d_in[5];
  const float* b2 = (const float*)d_in[6];

  const int E = in_sizes[0] / 2;
  const int Nu = in_sizes[1] / 64;
  const int Ni = in_sizes[2] / 64;
  const int N = Nu + Ni;
  const int* row = eidx;
  const int* colp = eidx + E;
  float* out = (float*)d_out;

  // workspace carve-out
  char* ws = (char*)d_ws;
  size_t off = 0;
  auto alloc = [&](size_t bytes) -> void* {
    void* p = ws + off;
    off += (bytes + 255) & ~(size_t)255;
    return p;
  };
  unsigned int* deg    = (unsigned int*)alloc((size_t)N * 4);
  unsigned int* cursor = (unsigned int*)alloc((size_t)N * 4);
  unsigned int* rowptr = (unsigned int*)alloc((size_t)(N + 1) * 4);
  float*        dis    = (float*)alloc((size_t)N * 4);
  unsigned int* incl   = (unsigned int*)alloc((size_t)N * 4);
  unsigned int* bsum   = (unsigned int*)alloc(1024 * 4);
  unsigned int* boff   = (unsigned int*)alloc(1024 * 4);
  int*          csr_src= (int*)alloc((size_t)E * 4);
  float*        csr_w  = (float*)alloc((size_t)E * 4);
  float*        S1     = (float*)alloc((size_t)N * 64 * 4);
  float*        cvec   = (float*)alloc((size_t)N * 4);
  (void)ws_size;

  hipMemsetAsync(deg, 0, (size_t)N * 4, stream);

  const int blkE = (E + 255) / 256;
  const int blkN = (N + 255) / 256;
  const int nblk = (N + 1023) / 1024;

  k_count<<<blkE, 256, 0, stream>>>(colp, E, deg);
  k_dis<<<blkN, 256, 0, stream>>>(deg, dis, N);
  k_scan1<<<nblk, 1024, 0, stream>>>(deg, incl, bsum, N);
  k_scan2<<<1, 64, 0, stream>>>(bsum, boff, nblk);
  k_scan3<<<blkN, 256, 0, stream>>>(deg, incl, boff, rowptr, cursor, N, E);
  k_fill<<<blkE, 256, 0, stream>>>(row, colp, E, dis, cursor, csr_src, csr_w);
  k_init<<<(N * 64 + 255) / 256, 256, 0, stream>>>(ue, ie, out, Nu, N);

  const int AGG_BLOCKS = 2048;
  for (int l = 0; l < 3; ++l) {
    int pcol = l * 64;
    int lcol = (l + 1) * 64;
    const float* W1l = W1 + (size_t)l * 64 * 64;
    const float* b1l = b1 + (size_t)l * 64;
    const float* W2l = W2 + (size_t)l * 64 * 64;
    const float* b2l = b2 + (size_t)l * 64;
    k_aggregate<<<AGG_BLOCKS, 256, 0, stream>>>(rowptr, csr_src, csr_w, out, S1, cvec, N, pcol);
    k_transform<<<AGG_BLOCKS, 256, 0, stream>>>(S1, cvec, out, W1l, b1l, W2l, b2l, N, pcol, lcol);
  }
}

// Round 2
// 562.472 us; speedup vs baseline: 1.1144x; 1.1144x over previous
//
#include <hip/hip_runtime.h>
#include <hip/hip_bf16.h>
#include <stdint.h>

// NGCF forward, node-factored form:
//   s1[i]   = sum_{e: col=i} norm_e * x[row_e]
//   aggr[i] = W1 s1[i] + W2 (x[i] .* s1[i]) + c[i]*(b1+b2),  c[i] = sum norm_e
//   x_next  = leaky_relu(aggr, 0.01)
// Layer outputs are written straight into their column block of out[N,256].

__global__ void k_count(const int* __restrict__ col, int E, unsigned int* __restrict__ deg) {
  int e = blockIdx.x * blockDim.x + threadIdx.x;
  if (e < E) atomicAdd(&deg[col[e]], 1u);
}

__global__ void k_dis(const unsigned int* __restrict__ deg, float* __restrict__ dis, int N) {
  int i = blockIdx.x * blockDim.x + threadIdx.x;
  if (i < N) {
    unsigned int d = deg[i];
    dis[i] = d ? rsqrtf((float)d) : 0.0f;
  }
}

// Hillis-Steele inclusive scan per 1024-block
__global__ void k_scan1(const unsigned int* __restrict__ deg, unsigned int* __restrict__ incl,
                        unsigned int* __restrict__ bsum, int N) {
  __shared__ unsigned int sm[1024];
  int t = threadIdx.x;
  int i = blockIdx.x * 1024 + t;
  unsigned int v = (i < N) ? deg[i] : 0u;
  sm[t] = v;
  __syncthreads();
  for (int off = 1; off < 1024; off <<= 1) {
    unsigned int u = (t >= off) ? sm[t - off] : 0u;
    __syncthreads();
    sm[t] += u;
    __syncthreads();
  }
  if (i < N) incl[i] = sm[t];
  if (t == 1023) bsum[blockIdx.x] = sm[1023];
}

__global__ void k_scan2(const unsigned int* __restrict__ bsum, unsigned int* __restrict__ boff, int nblk) {
  if (blockIdx.x == 0 && threadIdx.x == 0) {
    unsigned int a = 0;
    for (int i = 0; i < nblk; ++i) { boff[i] = a; a += bsum[i]; }
  }
}

__global__ void k_scan3(const unsigned int* __restrict__ deg, const unsigned int* __restrict__ incl,
                        const unsigned int* __restrict__ boff, unsigned int* __restrict__ rowptr,
                        unsigned int* __restrict__ cursor, int N, int E) {
  int i = blockIdx.x * blockDim.x + threadIdx.x;
  if (i < N) {
    unsigned int ex = incl[i] - deg[i] + boff[i >> 10];
    rowptr[i] = ex;
    cursor[i] = ex;
  }
  if (i == 0) rowptr[N] = (unsigned int)E;
}

__global__ void k_fill(const int* __restrict__ row, const int* __restrict__ col, int E,
                       const float* __restrict__ dis, unsigned int* __restrict__ cursor,
                       int* __restrict__ csr_src, float* __restrict__ csr_w) {
  int e = blockIdx.x * blockDim.x + threadIdx.x;
  if (e < E) {
    int r = row[e];
    int c = col[e];
    unsigned int pos = atomicAdd(&cursor[c], 1u);
    csr_src[pos] = r;
    csr_w[pos] = dis[r] * dis[c];
  }
}

// x0 = concat(user_emb, item_emb) -> out columns [0,64)
__global__ void k_init(const float* __restrict__ ue, const float* __restrict__ ie,
                       float* __restrict__ out, int Nu, int Ntot) {
  int idx = blockIdx.x * blockDim.x + threadIdx.x;
  if (idx >= Ntot * 64) return;
  int n = idx >> 6;
  int f = idx & 63;
  float v = (n < Nu) ? ue[idx] : ie[idx - Nu * 64];
  out[(size_t)n * 256 + f] = v;
}

// one wave per node; lane f accumulates feature f of s1.
// Edge loop unrolled x4 with independent accumulators so 4 gathers are
// in flight per wave (L3 hit latency ~300-500cy, avg degree ~10).
__global__ __launch_bounds__(256) void k_aggregate(
    const unsigned int* __restrict__ rowptr, const int* __restrict__ csr_src,
    const float* __restrict__ csr_w, const float* __restrict__ out,
    float* __restrict__ S1, float* __restrict__ cvec, int N, int pcol)
{
  int lane = threadIdx.x & 63;
  int wglobal = (blockIdx.x * (int)blockDim.x + (int)threadIdx.x) >> 6;
  int nwaves = (int)((gridDim.x * blockDim.x) >> 6);
  const float* xb = out + pcol + lane;
  for (int n0 = wglobal; n0 < N; n0 += nwaves) {
    int n = __builtin_amdgcn_readfirstlane(n0);
    unsigned int beg = rowptr[n];
    unsigned int end = rowptr[n + 1];
    float a0 = 0.0f, a1 = 0.0f, a2 = 0.0f, a3 = 0.0f;
    float c = 0.0f;
    unsigned int e = beg;
    for (; e + 4 <= end; e += 4) {
      int s0 = csr_src[e];
      int s1i = csr_src[e + 1];
      int s2 = csr_src[e + 2];
      int s3 = csr_src[e + 3];
      float w0 = csr_w[e];
      float w1 = csr_w[e + 1];
      float w2 = csr_w[e + 2];
      float w3 = csr_w[e + 3];
      float v0 = xb[(size_t)s0 * 256];
      float v1 = xb[(size_t)s1i * 256];
      float v2 = xb[(size_t)s2 * 256];
      float v3 = xb[(size_t)s3 * 256];
      a0 = fmaf(w0, v0, a0);
      a1 = fmaf(w1, v1, a1);
      a2 = fmaf(w2, v2, a2);
      a3 = fmaf(w3, v3, a3);
      c += (w0 + w1) + (w2 + w3);
    }
    for (; e < end; ++e) {
      int src = csr_src[e];
      float w = csr_w[e];
      a0 = fmaf(w, xb[(size_t)src * 256], a0);
      c += w;
    }
    float s1 = (a0 + a1) + (a2 + a3);
    S1[(size_t)n * 64 + lane] = s1;
    if (lane == 0) cvec[n] = c;
  }
}

// one wave per node; lane o holds rows W1[o][:], W2[o][:] in registers
// (128 VGPRs -- launch_bounds(256,1) lifts the occupancy-driven VGPR cap so
// they actually stay resident), s1/x broadcast via uniform scalar loads.
__global__ __launch_bounds__(256, 1) void k_transform(
    const float* __restrict__ S1, const float* __restrict__ cvec,
    float* __restrict__ out,
    const float* __restrict__ W1, const float* __restrict__ b1,
    const float* __restrict__ W2, const float* __restrict__ b2,
    int N, int pcol, int lcol)
{
  int lane = threadIdx.x & 63;
  float w1r[64], w2r[64];
#pragma unroll
  for (int f = 0; f < 64; ++f) {
    w1r[f] = W1[lane * 64 + f];
    w2r[f] = W2[lane * 64 + f];
  }
  float bb = b1[lane] + b2[lane];
  int wglobal = (blockIdx.x * (int)blockDim.x + (int)threadIdx.x) >> 6;
  int nwaves = (int)((gridDim.x * blockDim.x) >> 6);
  for (int n0 = wglobal; n0 < N; n0 += nwaves) {
    int n = __builtin_amdgcn_readfirstlane(n0);
    const float* s1p = S1 + (size_t)n * 64;
    const float* xp = out + (size_t)n * 256 + pcol;
    float acc = cvec[n] * bb;
#pragma unroll
    for (int f = 0; f < 64; ++f) {
      float s1f = s1p[f];
      float xf = xp[f];
      acc = fmaf(s1f, w1r[f], acc);
      acc = fmaf(xf * s1f, w2r[f], acc);
    }
    float r = (acc > 0.0f) ? acc : 0.01f * acc;
    out[(size_t)n * 256 + lcol + lane] = r;
  }
}

extern "C" void kernel_launch(void* const* d_in, const int* in_sizes, int n_in,
                              void* d_out, int out_size, void* d_ws, size_t ws_size,
                              hipStream_t stream) {
  const int* eidx = (const int*)d_in[0];
  const float* ue = (const float*)d_in[1];
  const float* ie = (const float*)d_in[2];
  const float* W1 = (const float*)d_in[3];
  const float* b1 = (const float*)d_in[4];
  const float* W2 = (const float*)d_in[5];
  const float* b2 = (const float*)d_in[6];

  const int E = in_sizes[0] / 2;
  const int Nu = in_sizes[1] / 64;
  const int Ni = in_sizes[2] / 64;
  const int N = Nu + Ni;
  const int* row = eidx;
  const int* colp = eidx + E;
  float* out = (float*)d_out;

  // workspace carve-out
  char* ws = (char*)d_ws;
  size_t off = 0;
  auto alloc = [&](size_t bytes) -> void* {
    void* p = ws + off;
    off += (bytes + 255) & ~(size_t)255;
    return p;
  };
  unsigned int* deg    = (unsigned int*)alloc((size_t)N * 4);
  unsigned int* cursor = (unsigned int*)alloc((size_t)N * 4);
  unsigned int* rowptr = (unsigned int*)alloc((size_t)(N + 1) * 4);
  float*        dis    = (float*)alloc((size_t)N * 4);
  unsigned int* incl   = (unsigned int*)alloc((size_t)N * 4);
  unsigned int* bsum   = (unsigned int*)alloc(1024 * 4);
  unsigned int* boff   = (unsigned int*)alloc(1024 * 4);
  int*          csr_src= (int*)alloc((size_t)E * 4);
  float*        csr_w  = (float*)alloc((size_t)E * 4);
  float*        S1     = (float*)alloc((size_t)N * 64 * 4);
  float*        cvec   = (float*)alloc((size_t)N * 4);
  (void)ws_size;

  hipMemsetAsync(deg, 0, (size_t)N * 4, stream);

  const int blkE = (E + 255) / 256;
  const int blkN = (N + 255) / 256;
  const int nblk = (N + 1023) / 1024;

  k_count<<<blkE, 256, 0, stream>>>(colp, E, deg);
  k_dis<<<blkN, 256, 0, stream>>>(deg, dis, N);
  k_scan1<<<nblk, 1024, 0, stream>>>(deg, incl, bsum, N);
  k_scan2<<<1, 64, 0, stream>>>(bsum, boff, nblk);
  k_scan3<<<blkN, 256, 0, stream>>>(deg, incl, boff, rowptr, cursor, N, E);
  k_fill<<<blkE, 256, 0, stream>>>(row, colp, E, dis, cursor, csr_src, csr_w);
  k_init<<<(N * 64 + 255) / 256, 256, 0, stream>>>(ue, ie, out, Nu, N);

  const int AGG_BLOCKS = 2048;
  for (int l = 0; l < 3; ++l) {
    int pcol = l * 64;
    int lcol = (l + 1) * 64;
    const float* W1l = W1 + (size_t)l * 64 * 64;
    const float* b1l = b1 + (size_t)l * 64;
    const float* W2l = W2 + (size_t)l * 64 * 64;
    const float* b2l = b2 + (size_t)l * 64;
    k_aggregate<<<AGG_BLOCKS, 256, 0, stream>>>(rowptr, csr_src, csr_w, out, S1, cvec, N, pcol);
    k_transform<<<AGG_BLOCKS, 256, 0, stream>>>(S1, cvec, out, W1l, b1l, W2l, b2l, N, pcol, lcol);
  }
}

// Round 3
// 511.617 us; speedup vs baseline: 1.2252x; 1.0994x over previous
//
#include <hip/hip_runtime.h>
#include <hip/hip_bf16.h>
#include <stdint.h>

// NGCF forward, node-factored form, fused per layer:
//   s1[i]   = sum_{e: col=i} norm_e * x[row_e]        (gather, lane = feature)
//   aggr[i] = W1 s1[i] + W2 (x[i].*s1[i]) + c[i]*(b1+b2)   (lane = output,
//             s1/h broadcast lane->all via v_readlane, weights pinned in VGPRs)
//   x_next  = leaky_relu(aggr, 0.01)
// Layer outputs go straight into their column block of out[N,256].

__device__ __forceinline__ float rdlane(float v, int l) {
  return __int_as_float(__builtin_amdgcn_readlane(__float_as_int(v), l));
}

__global__ void k_count(const int* __restrict__ col, int E, unsigned int* __restrict__ deg) {
  int e = blockIdx.x * blockDim.x + threadIdx.x;
  if (e < E) atomicAdd(&deg[col[e]], 1u);
}

__global__ void k_dis(const unsigned int* __restrict__ deg, float* __restrict__ dis, int N) {
  int i = blockIdx.x * blockDim.x + threadIdx.x;
  if (i < N) {
    unsigned int d = deg[i];
    dis[i] = d ? rsqrtf((float)d) : 0.0f;
  }
}

// Hillis-Steele inclusive scan per 1024-block
__global__ void k_scan1(const unsigned int* __restrict__ deg, unsigned int* __restrict__ incl,
                        unsigned int* __restrict__ bsum, int N) {
  __shared__ unsigned int sm[1024];
  int t = threadIdx.x;
  int i = blockIdx.x * 1024 + t;
  unsigned int v = (i < N) ? deg[i] : 0u;
  sm[t] = v;
  __syncthreads();
  for (int off = 1; off < 1024; off <<= 1) {
    unsigned int u = (t >= off) ? sm[t - off] : 0u;
    __syncthreads();
    sm[t] += u;
    __syncthreads();
  }
  if (i < N) incl[i] = sm[t];
  if (t == 1023) bsum[blockIdx.x] = sm[1023];
}

__global__ void k_scan2(const unsigned int* __restrict__ bsum, unsigned int* __restrict__ boff, int nblk) {
  if (blockIdx.x == 0 && threadIdx.x == 0) {
    unsigned int a = 0;
    for (int i = 0; i < nblk; ++i) { boff[i] = a; a += bsum[i]; }
  }
}

__global__ void k_scan3(const unsigned int* __restrict__ deg, const unsigned int* __restrict__ incl,
                        const unsigned int* __restrict__ boff, unsigned int* __restrict__ rowptr,
                        unsigned int* __restrict__ cursor, int N, int E) {
  int i = blockIdx.x * blockDim.x + threadIdx.x;
  if (i < N) {
    unsigned int ex = incl[i] - deg[i] + boff[i >> 10];
    rowptr[i] = ex;
    cursor[i] = ex;
  }
  if (i == 0) rowptr[N] = (unsigned int)E;
}

__global__ void k_fill(const int* __restrict__ row, const int* __restrict__ col, int E,
                       const float* __restrict__ dis, unsigned int* __restrict__ cursor,
                       int* __restrict__ csr_src, float* __restrict__ csr_w) {
  int e = blockIdx.x * blockDim.x + threadIdx.x;
  if (e < E) {
    int r = row[e];
    int c = col[e];
    unsigned int pos = atomicAdd(&cursor[c], 1u);
    csr_src[pos] = r;
    csr_w[pos] = dis[r] * dis[c];
  }
}

// x0 = concat(user_emb, item_emb) -> out columns [0,64)
__global__ void k_init(const float* __restrict__ ue, const float* __restrict__ ie,
                       float* __restrict__ out, int Nu, int Ntot) {
  int idx = blockIdx.x * blockDim.x + threadIdx.x;
  if (idx >= Ntot * 64) return;
  int n = idx >> 6;
  int f = idx & 63;
  float v = (n < Nu) ? ue[idx] : ie[idx - Nu * 64];
  out[(size_t)n * 256 + f] = v;
}

// Fused layer: one wave per node.
// Phase 1 (lane = feature f): s1 = sum_e w_e * x[src_e][f], c = sum_e w_e.
// Phase 2 (lane = output o): acc = c*(b1[o]+b2[o])
//        + sum_f  s1[f]*W1[o][f] + (x[n][f]*s1[f])*W2[o][f]
// with s1[f], h[f] broadcast from lane f via v_readlane (SGPR operand),
// and W1[o][:], W2[o][:] pinned in VGPRs via asm register-keep.
__global__ __launch_bounds__(256, 2) void k_fused(
    const unsigned int* __restrict__ rowptr, const int* __restrict__ csr_src,
    const float* __restrict__ csr_w, float* __restrict__ out,
    const float* __restrict__ W1, const float* __restrict__ b1,
    const float* __restrict__ W2, const float* __restrict__ b2,
    int N, int pcol, int lcol)
{
  int lane = threadIdx.x & 63;

  float w1r[64], w2r[64];
#pragma unroll
  for (int f = 0; f < 64; ++f) {
    w1r[f] = W1[lane * 64 + f];
    w2r[f] = W2[lane * 64 + f];
  }
  // Pin: value now defined by the asm -> RA cannot rematerialize the load
  // inside the node loop (round-2 counters showed it did exactly that).
#pragma unroll
  for (int f = 0; f < 64; ++f) {
    asm volatile("" : "+v"(w1r[f]), "+v"(w2r[f]));
  }
  float bb = b1[lane] + b2[lane];

  int wglobal = (blockIdx.x * (int)blockDim.x + (int)threadIdx.x) >> 6;
  int nwaves = (int)((gridDim.x * blockDim.x) >> 6);
  const float* xb = out + pcol + lane;

  for (int n0 = wglobal; n0 < N; n0 += nwaves) {
    int n = __builtin_amdgcn_readfirstlane(n0);
    unsigned int beg = rowptr[n];
    unsigned int end = rowptr[n + 1];

    // ---- gather phase (lane = feature) ----
    float a0 = 0.0f, a1 = 0.0f, a2 = 0.0f, a3 = 0.0f;
    float c = 0.0f;
    unsigned int e = beg;
    for (; e + 4 <= end; e += 4) {
      int s0 = csr_src[e];
      int s1i = csr_src[e + 1];
      int s2 = csr_src[e + 2];
      int s3 = csr_src[e + 3];
      float w0 = csr_w[e];
      float w1 = csr_w[e + 1];
      float w2 = csr_w[e + 2];
      float w3 = csr_w[e + 3];
      float v0 = xb[(size_t)s0 * 256];
      float v1 = xb[(size_t)s1i * 256];
      float v2 = xb[(size_t)s2 * 256];
      float v3 = xb[(size_t)s3 * 256];
      a0 = fmaf(w0, v0, a0);
      a1 = fmaf(w1, v1, a1);
      a2 = fmaf(w2, v2, a2);
      a3 = fmaf(w3, v3, a3);
      c += (w0 + w1) + (w2 + w3);
    }
    for (; e < end; ++e) {
      int src = csr_src[e];
      float w = csr_w[e];
      a0 = fmaf(w, xb[(size_t)src * 256], a0);
      c += w;
    }
    float s1 = (a0 + a1) + (a2 + a3);

    float xf = out[(size_t)n * 256 + pcol + lane];  // own row, coalesced
    float h = xf * s1;

    // ---- transform phase (lane = output o), 4 interleaved FMA chains ----
    float acc0 = c * bb, acc1 = 0.0f, acc2 = 0.0f, acc3 = 0.0f;
#pragma unroll
    for (int f = 0; f < 64; f += 2) {
      float sA = rdlane(s1, f);
      float hA = rdlane(h, f);
      float sB = rdlane(s1, f + 1);
      float hB = rdlane(h, f + 1);
      acc0 = fmaf(sA, w1r[f], acc0);
      acc1 = fmaf(hA, w2r[f], acc1);
      acc2 = fmaf(sB, w1r[f + 1], acc2);
      acc3 = fmaf(hB, w2r[f + 1], acc3);
    }
    float acc = (acc0 + acc1) + (acc2 + acc3);
    float r = (acc > 0.0f) ? acc : 0.01f * acc;
    out[(size_t)n * 256 + lcol + lane] = r;
  }
}

extern "C" void kernel_launch(void* const* d_in, const int* in_sizes, int n_in,
                              void* d_out, int out_size, void* d_ws, size_t ws_size,
                              hipStream_t stream) {
  const int* eidx = (const int*)d_in[0];
  const float* ue = (const float*)d_in[1];
  const float* ie = (const float*)d_in[2];
  const float* W1 = (const float*)d_in[3];
  const float* b1 = (const float*)d_in[4];
  const float* W2 = (const float*)d_in[5];
  const float* b2 = (const float*)d_in[6];

  const int E = in_sizes[0] / 2;
  const int Nu = in_sizes[1] / 64;
  const int Ni = in_sizes[2] / 64;
  const int N = Nu + Ni;
  const int* row = eidx;
  const int* colp = eidx + E;
  float* out = (float*)d_out;

  // workspace carve-out
  char* ws = (char*)d_ws;
  size_t off = 0;
  auto alloc = [&](size_t bytes) -> void* {
    void* p = ws + off;
    off += (bytes + 255) & ~(size_t)255;
    return p;
  };
  unsigned int* deg    = (unsigned int*)alloc((size_t)N * 4);
  unsigned int* cursor = (unsigned int*)alloc((size_t)N * 4);
  unsigned int* rowptr = (unsigned int*)alloc((size_t)(N + 1) * 4);
  float*        dis    = (float*)alloc((size_t)N * 4);
  unsigned int* incl   = (unsigned int*)alloc((size_t)N * 4);
  unsigned int* bsum   = (unsigned int*)alloc(1024 * 4);
  unsigned int* boff   = (unsigned int*)alloc(1024 * 4);
  int*          csr_src= (int*)alloc((size_t)E * 4);
  float*        csr_w  = (float*)alloc((size_t)E * 4);
  (void)ws_size;

  hipMemsetAsync(deg, 0, (size_t)N * 4, stream);

  const int blkE = (E + 255) / 256;
  const int blkN = (N + 255) / 256;
  const int nblk = (N + 1023) / 1024;

  k_count<<<blkE, 256, 0, stream>>>(colp, E, deg);
  k_dis<<<blkN, 256, 0, stream>>>(deg, dis, N);
  k_scan1<<<nblk, 1024, 0, stream>>>(deg, incl, bsum, N);
  k_scan2<<<1, 64, 0, stream>>>(bsum, boff, nblk);
  k_scan3<<<blkN, 256, 0, stream>>>(deg, incl, boff, rowptr, cursor, N, E);
  k_fill<<<blkE, 256, 0, stream>>>(row, colp, E, dis, cursor, csr_src, csr_w);
  k_init<<<(N * 64 + 255) / 256, 256, 0, stream>>>(ue, ie, out, Nu, N);

  const int BLOCKS = 2048;
  for (int l = 0; l < 3; ++l) {
    int pcol = l * 64;
    int lcol = (l + 1) * 64;
    const float* W1l = W1 + (size_t)l * 64 * 64;
    const float* b1l = b1 + (size_t)l * 64;
    const float* W2l = W2 + (size_t)l * 64 * 64;
    const float* b2l = b2 + (size_t)l * 64;
    k_fused<<<BLOCKS, 256, 0, stream>>>(rowptr, csr_src, csr_w, out,
                                        W1l, b1l, W2l, b2l, N, pcol, lcol);
  }
}

// Round 4
// 474.734 us; speedup vs baseline: 1.3204x; 1.0777x over previous
//
#include <hip/hip_runtime.h>
#include <stdint.h>

// NGCF forward. Node-factored:
//   s1[i] = sum_e norm_e * x[src_e],  c[i] = sum_e norm_e
//   aggr  = W1 s1 + W2 (x .* s1) + c*(b1+b2);  x' = leaky_relu(aggr)
// Gather: wave-per-node (lane = feature). Transform: MFMA 16x16x32 bf16,
// split hi/lo bf16 for ~fp32 accuracy, weights packed frag-order by k_prepw.

typedef __attribute__((ext_vector_type(8))) short short8v;
typedef __attribute__((ext_vector_type(4))) float f32x4;

__device__ __forceinline__ unsigned short f2bf_rne(float f) {
  unsigned int u = __float_as_uint(f);
  unsigned int r = u + 0x7FFFu + ((u >> 16) & 1u);
  return (unsigned short)(r >> 16);
}
__device__ __forceinline__ float bf2f(unsigned short h) {
  return __uint_as_float(((unsigned int)h) << 16);
}

__global__ void k_count(const int* __restrict__ col, int E, unsigned int* __restrict__ deg) {
  int e = blockIdx.x * blockDim.x + threadIdx.x;
  if (e < E) atomicAdd(&deg[col[e]], 1u);
}

__global__ void k_dis(const unsigned int* __restrict__ deg, float* __restrict__ dis, int N) {
  int i = blockIdx.x * blockDim.x + threadIdx.x;
  if (i < N) {
    unsigned int d = deg[i];
    dis[i] = d ? rsqrtf((float)d) : 0.0f;
  }
}

__global__ void k_scan1(const unsigned int* __restrict__ deg, unsigned int* __restrict__ incl,
                        unsigned int* __restrict__ bsum, int N) {
  __shared__ unsigned int sm[1024];
  int t = threadIdx.x;
  int i = blockIdx.x * 1024 + t;
  unsigned int v = (i < N) ? deg[i] : 0u;
  sm[t] = v;
  __syncthreads();
  for (int off = 1; off < 1024; off <<= 1) {
    unsigned int u = (t >= off) ? sm[t - off] : 0u;
    __syncthreads();
    sm[t] += u;
    __syncthreads();
  }
  if (i < N) incl[i] = sm[t];
  if (t == 1023) bsum[blockIdx.x] = sm[1023];
}

__global__ void k_scan2(const unsigned int* __restrict__ bsum, unsigned int* __restrict__ boff, int nblk) {
  if (blockIdx.x == 0 && threadIdx.x == 0) {
    unsigned int a = 0;
    for (int i = 0; i < nblk; ++i) { boff[i] = a; a += bsum[i]; }
  }
}

__global__ void k_scan3(const unsigned int* __restrict__ deg, const unsigned int* __restrict__ incl,
                        const unsigned int* __restrict__ boff, unsigned int* __restrict__ rowptr,
                        unsigned int* __restrict__ cursor, int N, int E) {
  int i = blockIdx.x * blockDim.x + threadIdx.x;
  if (i < N) {
    unsigned int ex = incl[i] - deg[i] + boff[i >> 10];
    rowptr[i] = ex;
    cursor[i] = ex;
  }
  if (i == 0) rowptr[N] = (unsigned int)E;
}

__global__ void k_fill(const int* __restrict__ row, const int* __restrict__ col, int E,
                       const float* __restrict__ dis, unsigned int* __restrict__ cursor,
                       int* __restrict__ csr_src, float* __restrict__ csr_w) {
  int e = blockIdx.x * blockDim.x + threadIdx.x;
  if (e < E) {
    int r = row[e];
    int c = col[e];
    unsigned int pos = atomicAdd(&cursor[c], 1u);
    csr_src[pos] = r;
    csr_w[pos] = dis[r] * dis[c];
  }
}

__global__ void k_init(const float* __restrict__ ue, const float* __restrict__ ie,
                       float* __restrict__ out, int Nu, int Ntot) {
  int idx = blockIdx.x * blockDim.x + threadIdx.x;
  if (idx >= Ntot * 64) return;
  int n = idx >> 6;
  int f = idx & 63;
  float v = (n < Nu) ? ue[idx] : ie[idx - Nu * 64];
  out[(size_t)n * 256 + f] = v;
}

// Pack W1/W2 (3 layers) into MFMA B-fragment order, split hi/lo bf16.
// Flat dst index = ((((((l*2+mat)*2+hl)*4+ob)*2+ks)*64+lane)*8+j)
// B[k][n] = W[out=n][k]; lane: n = 16*ob + (lane&15), k = 32*ks + 8*(lane>>4) + j.
// Also bbsum[l][o] = b1[l][o] + b2[l][o].
__global__ void k_prepw(const float* __restrict__ W1, const float* __restrict__ b1,
                        const float* __restrict__ W2, const float* __restrict__ b2,
                        unsigned short* __restrict__ Wf, float* __restrict__ bbsum) {
  int idx = blockIdx.x * blockDim.x + threadIdx.x;
  const int total = 3 * 2 * 2 * 4 * 2 * 64 * 8;  // 49152
  if (idx < total) {
    int j    = idx & 7;
    int lane = (idx >> 3) & 63;
    int ks   = (idx >> 9) & 1;
    int ob   = (idx >> 10) & 3;
    int hl   = (idx >> 12) & 1;
    int mat  = (idx >> 13) & 1;
    int l    = idx >> 14;
    int out_f = ob * 16 + (lane & 15);
    int k = ks * 32 + (lane >> 4) * 8 + j;
    const float* W = (mat ? W2 : W1) + (size_t)l * 64 * 64;
    float w = W[out_f * 64 + k];
    unsigned short hi = f2bf_rne(w);
    unsigned short val = hi;
    if (hl == 1) val = f2bf_rne(w - bf2f(hi));
    Wf[idx] = val;
  }
  if (idx < 3 * 64) {
    bbsum[idx] = b1[idx] + b2[idx];
  }
}

// One block = 64 nodes = 4 waves x 16 nodes. Gather (lane=feature) -> LDS,
// then per-wave MFMA transform on its own 16 rows.
__global__ __launch_bounds__(256, 3) void k_layer(
    const unsigned int* __restrict__ rowptr, const int* __restrict__ csr_src,
    const float* __restrict__ csr_w, float* __restrict__ out,
    const unsigned short* __restrict__ Wf,   // per-layer base, 16384 ushorts
    const float* __restrict__ bb,            // per-layer base, 64
    int N, int pcol, int lcol)
{
  __shared__ float tS[4][16][65];
  __shared__ float tH[4][16][65];
  __shared__ float cL[4][16];

  const int w = (int)threadIdx.x >> 6;
  const int lane = (int)threadIdx.x & 63;
  const int base = (int)blockIdx.x * 64 + w * 16;
  const float* xb = out + pcol + lane;

  // ---- gather phase ----
  for (int i = 0; i < 16; ++i) {
    int n = base + i;
    float a0 = 0.f, a1 = 0.f, a2 = 0.f, a3 = 0.f, c = 0.f, xf = 0.f;
    if (n < N) {
      unsigned int e = rowptr[n];
      unsigned int end = rowptr[n + 1];
      for (; e + 4 <= end; e += 4) {
        int s0 = csr_src[e];
        int s1i = csr_src[e + 1];
        int s2 = csr_src[e + 2];
        int s3 = csr_src[e + 3];
        float w0 = csr_w[e];
        float w1 = csr_w[e + 1];
        float w2 = csr_w[e + 2];
        float w3 = csr_w[e + 3];
        a0 = fmaf(w0, xb[(size_t)s0 * 256], a0);
        a1 = fmaf(w1, xb[(size_t)s1i * 256], a1);
        a2 = fmaf(w2, xb[(size_t)s2 * 256], a2);
        a3 = fmaf(w3, xb[(size_t)s3 * 256], a3);
        c += (w0 + w1) + (w2 + w3);
      }
      for (; e < end; ++e) {
        float we = csr_w[e];
        a0 = fmaf(we, xb[(size_t)csr_src[e] * 256], a0);
        c += we;
      }
      xf = out[(size_t)n * 256 + pcol + lane];
    }
    float s1 = (a0 + a1) + (a2 + a3);
    tS[w][i][lane] = s1;
    tH[w][i][lane] = xf * s1;
    if (lane == 0) cL[w][i] = c;
  }
  __syncthreads();

  // ---- MFMA transform phase (wave-private rows) ----
  const int m = lane & 15;
  const int g = lane >> 4;

  short8v AS[2][2], AH[2][2];  // [ks][hi/lo]
#pragma unroll
  for (int ks = 0; ks < 2; ++ks) {
    short8v sh, sl, hh, hlv;
#pragma unroll
    for (int j = 0; j < 8; ++j) {
      float vs = tS[w][m][ks * 32 + g * 8 + j];
      float vh = tH[w][m][ks * 32 + g * 8 + j];
      unsigned short h1 = f2bf_rne(vs);
      sh[j] = (short)h1;
      sl[j] = (short)f2bf_rne(vs - bf2f(h1));
      unsigned short h2 = f2bf_rne(vh);
      hh[j] = (short)h2;
      hlv[j] = (short)f2bf_rne(vh - bf2f(h2));
    }
    AS[ks][0] = sh; AS[ks][1] = sl;
    AH[ks][0] = hh; AH[ks][1] = hlv;
  }

  float bbv[4];
#pragma unroll
  for (int ob = 0; ob < 4; ++ob) bbv[ob] = bb[ob * 16 + m];
  float cn[4];
#pragma unroll
  for (int r = 0; r < 4; ++r) cn[r] = cL[w][g * 4 + r];

  auto ldW = [&](int mat, int hl, int ob, int ks) -> short8v {
    return *(const short8v*)(Wf + (size_t)((((((mat * 2 + hl) * 4 + ob) * 2 + ks) << 6) + lane) << 3));
  };

#pragma unroll
  for (int ob = 0; ob < 4; ++ob) {
    f32x4 a;
#pragma unroll
    for (int r = 0; r < 4; ++r) a[r] = cn[r] * bbv[ob];
#pragma unroll
    for (int ks = 0; ks < 2; ++ks) {
      short8v B1h = ldW(0, 0, ob, ks);
      short8v B1l = ldW(0, 1, ob, ks);
      short8v B2h = ldW(1, 0, ob, ks);
      short8v B2l = ldW(1, 1, ob, ks);
      a = __builtin_amdgcn_mfma_f32_16x16x32_bf16(AS[ks][0], B1h, a, 0, 0, 0);
      a = __builtin_amdgcn_mfma_f32_16x16x32_bf16(AS[ks][1], B1h, a, 0, 0, 0);
      a = __builtin_amdgcn_mfma_f32_16x16x32_bf16(AS[ks][0], B1l, a, 0, 0, 0);
      a = __builtin_amdgcn_mfma_f32_16x16x32_bf16(AH[ks][0], B2h, a, 0, 0, 0);
      a = __builtin_amdgcn_mfma_f32_16x16x32_bf16(AH[ks][1], B2h, a, 0, 0, 0);
      a = __builtin_amdgcn_mfma_f32_16x16x32_bf16(AH[ks][0], B2l, a, 0, 0, 0);
    }
    // C/D: col = lane&15 (out feature), row = g*4 + r (node within 16)
#pragma unroll
    for (int r = 0; r < 4; ++r) {
      int nl = g * 4 + r;
      int n = base + nl;
      if (n < N) {
        float v = a[r];
        v = (v > 0.0f) ? v : 0.01f * v;
        out[(size_t)n * 256 + lcol + ob * 16 + m] = v;
      }
    }
  }
}

extern "C" void kernel_launch(void* const* d_in, const int* in_sizes, int n_in,
                              void* d_out, int out_size, void* d_ws, size_t ws_size,
                              hipStream_t stream) {
  const int* eidx = (const int*)d_in[0];
  const float* ue = (const float*)d_in[1];
  const float* ie = (const float*)d_in[2];
  const float* W1 = (const float*)d_in[3];
  const float* b1 = (const float*)d_in[4];
  const float* W2 = (const float*)d_in[5];
  const float* b2 = (const float*)d_in[6];

  const int E = in_sizes[0] / 2;
  const int Nu = in_sizes[1] / 64;
  const int Ni = in_sizes[2] / 64;
  const int N = Nu + Ni;
  const int* row = eidx;
  const int* colp = eidx + E;
  float* out = (float*)d_out;

  char* ws = (char*)d_ws;
  size_t off = 0;
  auto alloc = [&](size_t bytes) -> void* {
    void* p = ws + off;
    off += (bytes + 255) & ~(size_t)255;
    return p;
  };
  unsigned int* deg    = (unsigned int*)alloc((size_t)N * 4);
  unsigned int* cursor = (unsigned int*)alloc((size_t)N * 4);
  unsigned int* rowptr = (unsigned int*)alloc((size_t)(N + 1) * 4);
  float*        dis    = (float*)alloc((size_t)N * 4);
  unsigned int* incl   = (unsigned int*)alloc((size_t)N * 4);
  unsigned int* bsum   = (unsigned int*)alloc(1024 * 4);
  unsigned int* boff   = (unsigned int*)alloc(1024 * 4);
  int*          csr_src= (int*)alloc((size_t)E * 4);
  float*        csr_w  = (float*)alloc((size_t)E * 4);
  unsigned short* Wf   = (unsigned short*)alloc((size_t)3 * 16384 * 2);
  float*        bbsum  = (float*)alloc((size_t)3 * 64 * 4);
  (void)ws_size;

  hipMemsetAsync(deg, 0, (size_t)N * 4, stream);

  const int blkE = (E + 255) / 256;
  const int blkN = (N + 255) / 256;
  const int nblk = (N + 1023) / 1024;

  k_count<<<blkE, 256, 0, stream>>>(colp, E, deg);
  k_dis<<<blkN, 256, 0, stream>>>(deg, dis, N);
  k_scan1<<<nblk, 1024, 0, stream>>>(deg, incl, bsum, N);
  k_scan2<<<1, 64, 0, stream>>>(bsum, boff, nblk);
  k_scan3<<<blkN, 256, 0, stream>>>(deg, incl, boff, rowptr, cursor, N, E);
  k_fill<<<blkE, 256, 0, stream>>>(row, colp, E, dis, cursor, csr_src, csr_w);
  k_init<<<(N * 64 + 255) / 256, 256, 0, stream>>>(ue, ie, out, Nu, N);
  k_prepw<<<192, 256, 0, stream>>>(W1, b1, W2, b2, Wf, bbsum);

  const int nt = (N + 63) / 64;
  for (int l = 0; l < 3; ++l) {
    int pcol = l * 64;
    int lcol = (l + 1) * 64;
    k_layer<<<nt, 256, 0, stream>>>(rowptr, csr_src, csr_w, out,
                                    Wf + (size_t)l * 16384, bbsum + (size_t)l * 64,
                                    N, pcol, lcol);
  }
}

// Round 5
// 373.686 us; speedup vs baseline: 1.6774x; 1.2704x over previous
//
#include <hip/hip_runtime.h>
#include <stdint.h>

// NGCF forward. Node-factored:
//   s1[i] = sum_e norm_e * x[src_e],  c[i] = sum_e norm_e
//   aggr  = W1 s1 + W2 (x .* s1) + c*(b1+b2);  x' = leaky_relu(aggr)
// Gather: wave-per-node-pair (lane = feature, 8 gather chains in flight).
// Transform: MFMA 16x16x32 bf16, split hi/lo bf16 (~fp32 accuracy),
// weights packed frag-order by k_prepw. Waves are fully independent
// (per-wave LDS tile, no block barrier).

typedef __attribute__((ext_vector_type(8))) short short8v;
typedef __attribute__((ext_vector_type(4))) float f32x4;

__device__ __forceinline__ unsigned short f2bf_rne(float f) {
  unsigned int u = __float_as_uint(f);
  unsigned int r = u + 0x7FFFu + ((u >> 16) & 1u);
  return (unsigned short)(r >> 16);
}
__device__ __forceinline__ float bf2f(unsigned short h) {
  return __uint_as_float(((unsigned int)h) << 16);
}

__global__ void k_count(const int* __restrict__ col, int E, unsigned int* __restrict__ deg) {
  int e = blockIdx.x * blockDim.x + threadIdx.x;
  if (e < E) atomicAdd(&deg[col[e]], 1u);
}

__global__ void k_dis(const unsigned int* __restrict__ deg, float* __restrict__ dis, int N) {
  int i = blockIdx.x * blockDim.x + threadIdx.x;
  if (i < N) {
    unsigned int d = deg[i];
    dis[i] = d ? rsqrtf((float)d) : 0.0f;
  }
}

__global__ void k_scan1(const unsigned int* __restrict__ deg, unsigned int* __restrict__ incl,
                        unsigned int* __restrict__ bsum, int N) {
  __shared__ unsigned int sm[1024];
  int t = threadIdx.x;
  int i = blockIdx.x * 1024 + t;
  unsigned int v = (i < N) ? deg[i] : 0u;
  sm[t] = v;
  __syncthreads();
  for (int off = 1; off < 1024; off <<= 1) {
    unsigned int u = (t >= off) ? sm[t - off] : 0u;
    __syncthreads();
    sm[t] += u;
    __syncthreads();
  }
  if (i < N) incl[i] = sm[t];
  if (t == 1023) bsum[blockIdx.x] = sm[1023];
}

__global__ void k_scan2(const unsigned int* __restrict__ bsum, unsigned int* __restrict__ boff, int nblk) {
  if (blockIdx.x == 0 && threadIdx.x == 0) {
    unsigned int a = 0;
    for (int i = 0; i < nblk; ++i) { boff[i] = a; a += bsum[i]; }
  }
}

__global__ void k_scan3(const unsigned int* __restrict__ deg, const unsigned int* __restrict__ incl,
                        const unsigned int* __restrict__ boff, unsigned int* __restrict__ rowptr,
                        unsigned int* __restrict__ cursor, int N, int E) {
  int i = blockIdx.x * blockDim.x + threadIdx.x;
  if (i < N) {
    unsigned int ex = incl[i] - deg[i] + boff[i >> 10];
    rowptr[i] = ex;
    cursor[i] = ex;
  }
  if (i == 0) rowptr[N] = (unsigned int)E;
}

__global__ void k_fill(const int* __restrict__ row, const int* __restrict__ col, int E,
                       const float* __restrict__ dis, unsigned int* __restrict__ cursor,
                       int* __restrict__ csr_src, float* __restrict__ csr_w) {
  int e = blockIdx.x * blockDim.x + threadIdx.x;
  if (e < E) {
    int r = row[e];
    int c = col[e];
    unsigned int pos = atomicAdd(&cursor[c], 1u);
    csr_src[pos] = r;
    csr_w[pos] = dis[r] * dis[c];
  }
}

__global__ void k_init(const float* __restrict__ ue, const float* __restrict__ ie,
                       float* __restrict__ out, int Nu, int Ntot) {
  int idx = blockIdx.x * blockDim.x + threadIdx.x;
  if (idx >= Ntot * 64) return;
  int n = idx >> 6;
  int f = idx & 63;
  float v = (n < Nu) ? ue[idx] : ie[idx - Nu * 64];
  out[(size_t)n * 256 + f] = v;
}

// Pack W1/W2 (3 layers) into MFMA B-fragment order, split hi/lo bf16.
// Flat dst index = ((((((l*2+mat)*2+hl)*4+ob)*2+ks)*64+lane)*8+j)
// B[k][n] = W[out=n][k]; lane: n = 16*ob + (lane&15), k = 32*ks + 8*(lane>>4) + j.
__global__ void k_prepw(const float* __restrict__ W1, const float* __restrict__ b1,
                        const float* __restrict__ W2, const float* __restrict__ b2,
                        unsigned short* __restrict__ Wf, float* __restrict__ bbsum) {
  int idx = blockIdx.x * blockDim.x + threadIdx.x;
  const int total = 3 * 2 * 2 * 4 * 2 * 64 * 8;  // 49152
  if (idx < total) {
    int j    = idx & 7;
    int lane = (idx >> 3) & 63;
    int ks   = (idx >> 9) & 1;
    int ob   = (idx >> 10) & 3;
    int hl   = (idx >> 12) & 1;
    int mat  = (idx >> 13) & 1;
    int l    = idx >> 14;
    int out_f = ob * 16 + (lane & 15);
    int k = ks * 32 + (lane >> 4) * 8 + j;
    const float* W = (mat ? W2 : W1) + (size_t)l * 64 * 64;
    float w = W[out_f * 64 + k];
    unsigned short hi = f2bf_rne(w);
    unsigned short val = hi;
    if (hl == 1) val = f2bf_rne(w - bf2f(hi));
    Wf[idx] = val;
  }
  if (idx < 3 * 64) {
    bbsum[idx] = b1[idx] + b2[idx];
  }
}

// One block = 64 nodes = 4 independent waves x 16 nodes.
// Gather: node PAIRS processed concurrently -> 8 gather chains in flight.
// MFMA phase reads x (Hadamard operand) straight from global (L2-hot),
// s1 goes through a per-wave LDS tile for the lane->frag transpose.
__global__ __launch_bounds__(256, 4) void k_layer(
    const unsigned int* __restrict__ rowptr, const int* __restrict__ csr_src,
    const float* __restrict__ csr_w, float* __restrict__ out,
    const unsigned short* __restrict__ Wf,   // per-layer base, 16384 ushorts
    const float* __restrict__ bb,            // per-layer base, 64
    int N, int pcol, int lcol)
{
  __shared__ float tS[4][16][65];
  __shared__ float cL[4][16];

  const int w = (int)threadIdx.x >> 6;
  const int lane = (int)threadIdx.x & 63;
  const int base = (int)blockIdx.x * 64 + w * 16;
  const float* xb = out + pcol + lane;

  // ---- gather phase: pairs (i, i+1), 8 chains in flight ----
  for (int i = 0; i < 16; i += 2) {
    int nA = base + i, nB = base + i + 1;
    unsigned int eA = 0, endA = 0, eB = 0, endB = 0;
    if (nA < N) { eA = rowptr[nA]; endA = rowptr[nA + 1]; }
    if (nB < N) { eB = rowptr[nB]; endB = rowptr[nB + 1]; }
    float aA0 = 0.f, aA1 = 0.f, aA2 = 0.f, aA3 = 0.f, cA = 0.f;
    float aB0 = 0.f, aB1 = 0.f, aB2 = 0.f, aB3 = 0.f, cB = 0.f;
    while (eA + 4 <= endA && eB + 4 <= endB) {
      int sA0 = csr_src[eA],     sA1 = csr_src[eA + 1],
          sA2 = csr_src[eA + 2], sA3 = csr_src[eA + 3];
      int sB0 = csr_src[eB],     sB1 = csr_src[eB + 1],
          sB2 = csr_src[eB + 2], sB3 = csr_src[eB + 3];
      float wA0 = csr_w[eA],     wA1 = csr_w[eA + 1],
            wA2 = csr_w[eA + 2], wA3 = csr_w[eA + 3];
      float wB0 = csr_w[eB],     wB1 = csr_w[eB + 1],
            wB2 = csr_w[eB + 2], wB3 = csr_w[eB + 3];
      float vA0 = xb[(size_t)sA0 * 256], vA1 = xb[(size_t)sA1 * 256],
            vA2 = xb[(size_t)sA2 * 256], vA3 = xb[(size_t)sA3 * 256];
      float vB0 = xb[(size_t)sB0 * 256], vB1 = xb[(size_t)sB1 * 256],
            vB2 = xb[(size_t)sB2 * 256], vB3 = xb[(size_t)sB3 * 256];
      aA0 = fmaf(wA0, vA0, aA0); aA1 = fmaf(wA1, vA1, aA1);
      aA2 = fmaf(wA2, vA2, aA2); aA3 = fmaf(wA3, vA3, aA3);
      aB0 = fmaf(wB0, vB0, aB0); aB1 = fmaf(wB1, vB1, aB1);
      aB2 = fmaf(wB2, vB2, aB2); aB3 = fmaf(wB3, vB3, aB3);
      cA += (wA0 + wA1) + (wA2 + wA3);
      cB += (wB0 + wB1) + (wB2 + wB3);
      eA += 4; eB += 4;
    }
    while (eA + 4 <= endA) {
      int s0 = csr_src[eA], s1i = csr_src[eA + 1], s2 = csr_src[eA + 2], s3 = csr_src[eA + 3];
      float w0 = csr_w[eA], w1 = csr_w[eA + 1], w2 = csr_w[eA + 2], w3 = csr_w[eA + 3];
      aA0 = fmaf(w0, xb[(size_t)s0 * 256], aA0);
      aA1 = fmaf(w1, xb[(size_t)s1i * 256], aA1);
      aA2 = fmaf(w2, xb[(size_t)s2 * 256], aA2);
      aA3 = fmaf(w3, xb[(size_t)s3 * 256], aA3);
      cA += (w0 + w1) + (w2 + w3);
      eA += 4;
    }
    while (eB + 4 <= endB) {
      int s0 = csr_src[eB], s1i = csr_src[eB + 1], s2 = csr_src[eB + 2], s3 = csr_src[eB + 3];
      float w0 = csr_w[eB], w1 = csr_w[eB + 1], w2 = csr_w[eB + 2], w3 = csr_w[eB + 3];
      aB0 = fmaf(w0, xb[(size_t)s0 * 256], aB0);
      aB1 = fmaf(w1, xb[(size_t)s1i * 256], aB1);
      aB2 = fmaf(w2, xb[(size_t)s2 * 256], aB2);
      aB3 = fmaf(w3, xb[(size_t)s3 * 256], aB3);
      cB += (w0 + w1) + (w2 + w3);
      eB += 4;
    }
    for (; eA < endA; ++eA) {
      float we = csr_w[eA];
      aA0 = fmaf(we, xb[(size_t)csr_src[eA] * 256], aA0);
      cA += we;
    }
    for (; eB < endB; ++eB) {
      float we = csr_w[eB];
      aB0 = fmaf(we, xb[(size_t)csr_src[eB] * 256], aB0);
      cB += we;
    }
    tS[w][i][lane]     = (aA0 + aA1) + (aA2 + aA3);
    tS[w][i + 1][lane] = (aB0 + aB1) + (aB2 + aB3);
    if (lane == 0) { cL[w][i] = cA; cL[w][i + 1] = cB; }
  }
  // NO __syncthreads: tS[w]/cL[w] are wave-private (compiler orders LDS ops).

  // ---- MFMA transform phase ----
  const int m = lane & 15;
  const int g = lane >> 4;
  const int rn = (base + m < N) ? (base + m) : (N - 1);  // clamp addr; s1=0 there

  short8v AS[2][2], AH[2][2];  // [ks][hi/lo]
#pragma unroll
  for (int ks = 0; ks < 2; ++ks) {
    const float* xrow = out + (size_t)rn * 256 + pcol + ks * 32 + g * 8;
    f32x4 x0 = *(const f32x4*)(xrow);
    f32x4 x1 = *(const f32x4*)(xrow + 4);
    short8v sh, sl, hh, hlv;
#pragma unroll
    for (int j = 0; j < 8; ++j) {
      float vs = tS[w][m][ks * 32 + g * 8 + j];
      float vx = (j < 4) ? x0[j & 3] : x1[j & 3];
      float vh = vx * vs;
      unsigned short h1 = f2bf_rne(vs);
      sh[j] = (short)h1;
      sl[j] = (short)f2bf_rne(vs - bf2f(h1));
      unsigned short h2 = f2bf_rne(vh);
      hh[j] = (short)h2;
      hlv[j] = (short)f2bf_rne(vh - bf2f(h2));
    }
    AS[ks][0] = sh; AS[ks][1] = sl;
    AH[ks][0] = hh; AH[ks][1] = hlv;
  }

  float bbv[4];
#pragma unroll
  for (int ob = 0; ob < 4; ++ob) bbv[ob] = bb[ob * 16 + m];
  float cn[4];
#pragma unroll
  for (int r = 0; r < 4; ++r) cn[r] = cL[w][g * 4 + r];

  auto ldW = [&](int mat, int hl, int ob, int ks) -> short8v {
    return *(const short8v*)(Wf + (size_t)((((((mat * 2 + hl) * 4 + ob) * 2 + ks) << 6) + lane) << 3));
  };

#pragma unroll
  for (int ob = 0; ob < 4; ++ob) {
    f32x4 a;
#pragma unroll
    for (int r = 0; r < 4; ++r) a[r] = cn[r] * bbv[ob];
#pragma unroll
    for (int ks = 0; ks < 2; ++ks) {
      short8v B1h = ldW(0, 0, ob, ks);
      short8v B1l = ldW(0, 1, ob, ks);
      short8v B2h = ldW(1, 0, ob, ks);
      short8v B2l = ldW(1, 1, ob, ks);
      a = __builtin_amdgcn_mfma_f32_16x16x32_bf16(AS[ks][0], B1h, a, 0, 0, 0);
      a = __builtin_amdgcn_mfma_f32_16x16x32_bf16(AS[ks][1], B1h, a, 0, 0, 0);
      a = __builtin_amdgcn_mfma_f32_16x16x32_bf16(AS[ks][0], B1l, a, 0, 0, 0);
      a = __builtin_amdgcn_mfma_f32_16x16x32_bf16(AH[ks][0], B2h, a, 0, 0, 0);
      a = __builtin_amdgcn_mfma_f32_16x16x32_bf16(AH[ks][1], B2h, a, 0, 0, 0);
      a = __builtin_amdgcn_mfma_f32_16x16x32_bf16(AH[ks][0], B2l, a, 0, 0, 0);
    }
    // C/D: col = lane&15 (out feature), row = g*4 + r (node within 16)
#pragma unroll
    for (int r = 0; r < 4; ++r) {
      int n = base + g * 4 + r;
      if (n < N) {
        float v = a[r];
        v = (v > 0.0f) ? v : 0.01f * v;
        out[(size_t)n * 256 + lcol + ob * 16 + m] = v;
      }
    }
  }
}

extern "C" void kernel_launch(void* const* d_in, const int* in_sizes, int n_in,
                              void* d_out, int out_size, void* d_ws, size_t ws_size,
                              hipStream_t stream) {
  const int* eidx = (const int*)d_in[0];
  const float* ue = (const float*)d_in[1];
  const float* ie = (const float*)d_in[2];
  const float* W1 = (const float*)d_in[3];
  const float* b1 = (const float*)d_in[4];
  const float* W2 = (const float*)d_in[5];
  const float* b2 = (const float*)d_in[6];

  const int E = in_sizes[0] / 2;
  const int Nu = in_sizes[1] / 64;
  const int Ni = in_sizes[2] / 64;
  const int N = Nu + Ni;
  const int* row = eidx;
  const int* colp = eidx + E;
  float* out = (float*)d_out;

  char* ws = (char*)d_ws;
  size_t off = 0;
  auto alloc = [&](size_t bytes) -> void* {
    void* p = ws + off;
    off += (bytes + 255) & ~(size_t)255;
    return p;
  };
  unsigned int* deg    = (unsigned int*)alloc((size_t)N * 4);
  unsigned int* cursor = (unsigned int*)alloc((size_t)N * 4);
  unsigned int* rowptr = (unsigned int*)alloc((size_t)(N + 1) * 4);
  float*        dis    = (float*)alloc((size_t)N * 4);
  unsigned int* incl   = (unsigned int*)alloc((size_t)N * 4);
  unsigned int* bsum   = (unsigned int*)alloc(1024 * 4);
  unsigned int* boff   = (unsigned int*)alloc(1024 * 4);
  int*          csr_src= (int*)alloc((size_t)E * 4);
  float*        csr_w  = (float*)alloc((size_t)E * 4);
  unsigned short* Wf   = (unsigned short*)alloc((size_t)3 * 16384 * 2);
  float*        bbsum  = (float*)alloc((size_t)3 * 64 * 4);
  (void)ws_size;

  hipMemsetAsync(deg, 0, (size_t)N * 4, stream);

  const int blkE = (E + 255) / 256;
  const int blkN = (N + 255) / 256;
  const int nblk = (N + 1023) / 1024;

  k_count<<<blkE, 256, 0, stream>>>(colp, E, deg);
  k_dis<<<blkN, 256, 0, stream>>>(deg, dis, N);
  k_scan1<<<nblk, 1024, 0, stream>>>(deg, incl, bsum, N);
  k_scan2<<<1, 64, 0, stream>>>(bsum, boff, nblk);
  k_scan3<<<blkN, 256, 0, stream>>>(deg, incl, boff, rowptr, cursor, N, E);
  k_fill<<<blkE, 256, 0, stream>>>(row, colp, E, dis, cursor, csr_src, csr_w);
  k_init<<<(N * 64 + 255) / 256, 256, 0, stream>>>(ue, ie, out, Nu, N);
  k_prepw<<<192, 256, 0, stream>>>(W1, b1, W2, b2, Wf, bbsum);

  const int nt = (N + 63) / 64;
  for (int l = 0; l < 3; ++l) {
    int pcol = l * 64;
    int lcol = (l + 1) * 64;
    k_layer<<<nt, 256, 0, stream>>>(rowptr, csr_src, csr_w, out,
                                    Wf + (size_t)l * 16384, bbsum + (size_t)l * 64,
                                    N, pcol, lcol);
  }
}

// Round 6
// 302.957 us; speedup vs baseline: 2.0690x; 1.2335x over previous
//
#include <hip/hip_runtime.h>
#include <stdint.h>

// NGCF forward. Node-factored:
//   s1[i] = sum_e norm_e * x[src_e],  c[i] = sum_e norm_e
//   aggr  = W1 s1 + W2 (x .* s1) + c*(b1+b2);  x' = leaky_relu(aggr)
// Gather: 16-node blocks (128 thr / 2 waves). Each wave gathers 8 nodes as
// pairs; per node, lanes split half-wave over EDGES (2 edges/load) and cover
// features as float2 (lane j -> features 2j,2j+1). CSR payload interleaved
// (src,w) 8B. Transform: MFMA 16x16x32 bf16 split hi/lo (~fp32), the two
// waves split the 4 output-blocks (2 each).

typedef __attribute__((ext_vector_type(8))) short short8v;
typedef __attribute__((ext_vector_type(4))) float f32x4;
typedef __attribute__((ext_vector_type(2))) float f32x2;

struct EdgeIW { int src; float w; };  // interleaved CSR payload, 8B

__device__ __forceinline__ unsigned short f2bf_rne(float f) {
  unsigned int u = __float_as_uint(f);
  unsigned int r = u + 0x7FFFu + ((u >> 16) & 1u);
  return (unsigned short)(r >> 16);
}
__device__ __forceinline__ float bf2f(unsigned short h) {
  return __uint_as_float(((unsigned int)h) << 16);
}

__global__ void k_count(const int* __restrict__ col, int E, unsigned int* __restrict__ deg) {
  int e = blockIdx.x * blockDim.x + threadIdx.x;
  if (e < E) atomicAdd(&deg[col[e]], 1u);
}

__global__ void k_scan1(const unsigned int* __restrict__ deg, unsigned int* __restrict__ incl,
                        unsigned int* __restrict__ bsum, int N) {
  __shared__ unsigned int sm[1024];
  int t = threadIdx.x;
  int i = blockIdx.x * 1024 + t;
  unsigned int v = (i < N) ? deg[i] : 0u;
  sm[t] = v;
  __syncthreads();
  for (int off = 1; off < 1024; off <<= 1) {
    unsigned int u = (t >= off) ? sm[t - off] : 0u;
    __syncthreads();
    sm[t] += u;
    __syncthreads();
  }
  if (i < N) incl[i] = sm[t];
  if (t == 1023) bsum[blockIdx.x] = sm[1023];
}

__global__ void k_scan2(const unsigned int* __restrict__ bsum, unsigned int* __restrict__ boff, int nblk) {
  if (blockIdx.x == 0 && threadIdx.x == 0) {
    unsigned int a = 0;
    for (int i = 0; i < nblk; ++i) { boff[i] = a; a += bsum[i]; }
  }
}

// rowptr/cursor + dis (fused)
__global__ void k_scan3(const unsigned int* __restrict__ deg, const unsigned int* __restrict__ incl,
                        const unsigned int* __restrict__ boff, unsigned int* __restrict__ rowptr,
                        unsigned int* __restrict__ cursor, float* __restrict__ dis, int N, int E) {
  int i = blockIdx.x * blockDim.x + threadIdx.x;
  if (i < N) {
    unsigned int ex = incl[i] - deg[i] + boff[i >> 10];
    rowptr[i] = ex;
    cursor[i] = ex;
    unsigned int d = deg[i];
    dis[i] = d ? rsqrtf((float)d) : 0.0f;
  }
  if (i == 0) rowptr[N] = (unsigned int)E;
}

__global__ void k_fill(const int* __restrict__ row, const int* __restrict__ col, int E,
                       const float* __restrict__ dis, unsigned int* __restrict__ cursor,
                       EdgeIW* __restrict__ iw) {
  int e = blockIdx.x * blockDim.x + threadIdx.x;
  if (e < E) {
    int r = row[e];
    int c = col[e];
    unsigned int pos = atomicAdd(&cursor[c], 1u);
    EdgeIW p;
    p.src = r;
    p.w = dis[r] * dis[c];
    iw[pos] = p;
  }
}

// x0 = concat(user_emb, item_emb) -> out columns [0,64), float4 vectorized
__global__ void k_init(const float* __restrict__ ue, const float* __restrict__ ie,
                       float* __restrict__ out, int Nu, int Ntot) {
  int idx = blockIdx.x * blockDim.x + threadIdx.x;
  if (idx >= Ntot * 16) return;
  int n = idx >> 4;
  int q = idx & 15;
  f32x4 v = (n < Nu) ? *(const f32x4*)(ue + (size_t)n * 64 + q * 4)
                     : *(const f32x4*)(ie + (size_t)(n - Nu) * 64 + q * 4);
  *(f32x4*)(out + (size_t)n * 256 + q * 4) = v;
}

// Pack W1/W2 (3 layers) into MFMA B-fragment order, split hi/lo bf16.
// Flat dst index = ((((((l*2+mat)*2+hl)*4+ob)*2+ks)*64+lane)*8+j)
// B[k][n] = W[out=n][k]; lane: n = 16*ob + (lane&15), k = 32*ks + 8*(lane>>4) + j.
__global__ void k_prepw(const float* __restrict__ W1, const float* __restrict__ b1,
                        const float* __restrict__ W2, const float* __restrict__ b2,
                        unsigned short* __restrict__ Wf, float* __restrict__ bbsum) {
  int idx = blockIdx.x * blockDim.x + threadIdx.x;
  const int total = 3 * 2 * 2 * 4 * 2 * 64 * 8;  // 49152
  if (idx < total) {
    int j    = idx & 7;
    int lane = (idx >> 3) & 63;
    int ks   = (idx >> 9) & 1;
    int ob   = (idx >> 10) & 3;
    int hl   = (idx >> 12) & 1;
    int mat  = (idx >> 13) & 1;
    int l    = idx >> 14;
    int out_f = ob * 16 + (lane & 15);
    int k = ks * 32 + (lane >> 4) * 8 + j;
    const float* W = (mat ? W2 : W1) + (size_t)l * 64 * 64;
    float w = W[out_f * 64 + k];
    unsigned short hi = f2bf_rne(w);
    unsigned short val = hi;
    if (hl == 1) val = f2bf_rne(w - bf2f(hi));
    Wf[idx] = val;
  }
  if (idx < 3 * 64) {
    bbsum[idx] = b1[idx] + b2[idx];
  }
}

// One block = 16 nodes = 2 waves x 8 nodes. float2 two-edge gather.
__global__ __launch_bounds__(128, 7) void k_layer(
    const unsigned int* __restrict__ rowptr, const EdgeIW* __restrict__ iw,
    float* __restrict__ out,
    const unsigned short* __restrict__ Wf,   // per-layer base, 16384 ushorts
    const float* __restrict__ bb,            // per-layer base, 64
    int N, int pcol, int lcol)
{
  __shared__ float tS[16][66];
  __shared__ float cL[16];

  const int w = (int)threadIdx.x >> 6;
  const int lane = (int)threadIdx.x & 63;
  const int h = lane >> 5;     // which edge of the 2-edge batch
  const int j = lane & 31;     // feature-pair index (features 2j, 2j+1)
  const int base = (int)blockIdx.x * 16;
  const float* xq = out + pcol + 2 * j;

#define FMA2(acc, p, v) { acc.x = fmaf(p.w, v.x, acc.x); acc.y = fmaf(p.w, v.y, acc.y); }
#define LD2(p) (*(const f32x2*)(xq + (size_t)(p).src * 256))

  // ---- gather phase: wave w owns rows [8w,8w+8), as 4 node-pairs ----
  for (int i0 = 0; i0 < 8; i0 += 2) {
    const int iA = w * 8 + i0, iB = iA + 1;
    int nA = base + iA, nB = base + iB;
    unsigned int eA = 0, endA = 0, eB = 0, endB = 0;
    if (nA < N) { eA = rowptr[nA]; endA = rowptr[nA + 1]; }
    if (nB < N) { eB = rowptr[nB]; endB = rowptr[nB + 1]; }
    f32x2 aA0 = {0.f, 0.f}, aA1 = {0.f, 0.f}, aB0 = {0.f, 0.f}, aB1 = {0.f, 0.f};
    float cA = 0.f, cB = 0.f;
    while (eA + 4 <= endA && eB + 4 <= endB) {
      EdgeIW pA0 = iw[eA + h];
      EdgeIW pA1 = iw[eA + 2 + h];
      EdgeIW pB0 = iw[eB + h];
      EdgeIW pB1 = iw[eB + 2 + h];
      f32x2 vA0 = LD2(pA0);
      f32x2 vA1 = LD2(pA1);
      f32x2 vB0 = LD2(pB0);
      f32x2 vB1 = LD2(pB1);
      FMA2(aA0, pA0, vA0); FMA2(aA1, pA1, vA1);
      FMA2(aB0, pB0, vB0); FMA2(aB1, pB1, vB1);
      cA += pA0.w + pA1.w;
      cB += pB0.w + pB1.w;
      eA += 4; eB += 4;
    }
    while (eA + 4 <= endA) {
      EdgeIW p0 = iw[eA + h];
      EdgeIW p1 = iw[eA + 2 + h];
      f32x2 v0 = LD2(p0);
      f32x2 v1 = LD2(p1);
      FMA2(aA0, p0, v0); FMA2(aA1, p1, v1);
      cA += p0.w + p1.w;
      eA += 4;
    }
    while (eB + 4 <= endB) {
      EdgeIW p0 = iw[eB + h];
      EdgeIW p1 = iw[eB + 2 + h];
      f32x2 v0 = LD2(p0);
      f32x2 v1 = LD2(p1);
      FMA2(aB0, p0, v0); FMA2(aB1, p1, v1);
      cB += p0.w + p1.w;
      eB += 4;
    }
    if (eA < endA) {
      int r = (int)(endA - eA);
      if (h < r) { EdgeIW p = iw[eA + h]; f32x2 v = LD2(p); FMA2(aA0, p, v); cA += p.w; }
      if (2 + h < r) { EdgeIW p = iw[eA + 2 + h]; f32x2 v = LD2(p); FMA2(aA1, p, v); cA += p.w; }
    }
    if (eB < endB) {
      int r = (int)(endB - eB);
      if (h < r) { EdgeIW p = iw[eB + h]; f32x2 v = LD2(p); FMA2(aB0, p, v); cB += p.w; }
      if (2 + h < r) { EdgeIW p = iw[eB + 2 + h]; f32x2 v = LD2(p); FMA2(aB1, p, v); cB += p.w; }
    }
    // combine 2 chains, then the two half-waves (edge slots)
    f32x2 sA, sB;
    sA.x = aA0.x + aA1.x; sA.y = aA0.y + aA1.y;
    sB.x = aB0.x + aB1.x; sB.y = aB0.y + aB1.y;
    sA.x += __shfl_xor(sA.x, 32); sA.y += __shfl_xor(sA.y, 32);
    sB.x += __shfl_xor(sB.x, 32); sB.y += __shfl_xor(sB.y, 32);
    cA += __shfl_xor(cA, 32);
    cB += __shfl_xor(cB, 32);
    if (h == 0) {
      *(f32x2*)&tS[iA][2 * j] = sA;
      *(f32x2*)&tS[iB][2 * j] = sB;
    }
    if (lane == 0) { cL[iA] = cA; cL[iB] = cB; }
  }
  __syncthreads();

  // ---- MFMA transform: wave w handles output blocks ob = 2w, 2w+1 ----
  const int m = lane & 15;
  const int g = lane >> 4;
  const int rn = (base + m < N) ? (base + m) : (N - 1);

  float bb0 = bb[(2 * w + 0) * 16 + m];
  float bb1 = bb[(2 * w + 1) * 16 + m];
  float cn[4];
#pragma unroll
  for (int r = 0; r < 4; ++r) cn[r] = cL[g * 4 + r];

  f32x4 accP, accQ;
#pragma unroll
  for (int r = 0; r < 4; ++r) { accP[r] = cn[r] * bb0; accQ[r] = cn[r] * bb1; }

  auto ldW = [&](int mat, int hl, int ob, int ks) -> short8v {
    return *(const short8v*)(Wf + (size_t)((((((mat * 2 + hl) * 4 + ob) * 2 + ks) << 6) + lane) << 3));
  };

#pragma unroll
  for (int ks = 0; ks < 2; ++ks) {
    const float* xrow = out + (size_t)rn * 256 + pcol + ks * 32 + g * 8;
    f32x4 x0 = *(const f32x4*)xrow;
    f32x4 x1 = *(const f32x4*)(xrow + 4);
    short8v ASh, ASl, AHh, AHl;
#pragma unroll
    for (int jj = 0; jj < 8; ++jj) {
      float vs = tS[m][ks * 32 + g * 8 + jj];
      float vx = (jj < 4) ? x0[jj & 3] : x1[jj & 3];
      float vh = vx * vs;
      unsigned short h1 = f2bf_rne(vs);
      ASh[jj] = (short)h1;
      ASl[jj] = (short)f2bf_rne(vs - bf2f(h1));
      unsigned short h2 = f2bf_rne(vh);
      AHh[jj] = (short)h2;
      AHl[jj] = (short)f2bf_rne(vh - bf2f(h2));
    }
    {
      const int ob = 2 * w;
      short8v B1h = ldW(0, 0, ob, ks), B1l = ldW(0, 1, ob, ks);
      short8v B2h = ldW(1, 0, ob, ks), B2l = ldW(1, 1, ob, ks);
      accP = __builtin_amdgcn_mfma_f32_16x16x32_bf16(ASh, B1h, accP, 0, 0, 0);
      accP = __builtin_amdgcn_mfma_f32_16x16x32_bf16(ASl, B1h, accP, 0, 0, 0);
      accP = __builtin_amdgcn_mfma_f32_16x16x32_bf16(ASh, B1l, accP, 0, 0, 0);
      accP = __builtin_amdgcn_mfma_f32_16x16x32_bf16(AHh, B2h, accP, 0, 0, 0);
      accP = __builtin_amdgcn_mfma_f32_16x16x32_bf16(AHl, B2h, accP, 0, 0, 0);
      accP = __builtin_amdgcn_mfma_f32_16x16x32_bf16(AHh, B2l, accP, 0, 0, 0);
    }
    {
      const int ob = 2 * w + 1;
      short8v B1h = ldW(0, 0, ob, ks), B1l = ldW(0, 1, ob, ks);
      short8v B2h = ldW(1, 0, ob, ks), B2l = ldW(1, 1, ob, ks);
      accQ = __builtin_amdgcn_mfma_f32_16x16x32_bf16(ASh, B1h, accQ, 0, 0, 0);
      accQ = __builtin_amdgcn_mfma_f32_16x16x32_bf16(ASl, B1h, accQ, 0, 0, 0);
      accQ = __builtin_amdgcn_mfma_f32_16x16x32_bf16(ASh, B1l, accQ, 0, 0, 0);
      accQ = __builtin_amdgcn_mfma_f32_16x16x32_bf16(AHh, B2h, accQ, 0, 0, 0);
      accQ = __builtin_amdgcn_mfma_f32_16x16x32_bf16(AHl, B2h, accQ, 0, 0, 0);
      accQ = __builtin_amdgcn_mfma_f32_16x16x32_bf16(AHh, B2l, accQ, 0, 0, 0);
    }
  }
  // C/D: col = lane&15 (out feature), row = g*4 + r (node within 16)
#pragma unroll
  for (int r = 0; r < 4; ++r) {
    int n = base + g * 4 + r;
    if (n < N) {
      float v = accP[r];
      v = (v > 0.0f) ? v : 0.01f * v;
      out[(size_t)n * 256 + lcol + (2 * w) * 16 + m] = v;
      float q = accQ[r];
      q = (q > 0.0f) ? q : 0.01f * q;
      out[(size_t)n * 256 + lcol + (2 * w + 1) * 16 + m] = q;
    }
  }
#undef FMA2
#undef LD2
}

extern "C" void kernel_launch(void* const* d_in, const int* in_sizes, int n_in,
                              void* d_out, int out_size, void* d_ws, size_t ws_size,
                              hipStream_t stream) {
  const int* eidx = (const int*)d_in[0];
  const float* ue = (const float*)d_in[1];
  const float* ie = (const float*)d_in[2];
  const float* W1 = (const float*)d_in[3];
  const float* b1 = (const float*)d_in[4];
  const float* W2 = (const float*)d_in[5];
  const float* b2 = (const float*)d_in[6];

  const int E = in_sizes[0] / 2;
  const int Nu = in_sizes[1] / 64;
  const int Ni = in_sizes[2] / 64;
  const int N = Nu + Ni;
  const int* row = eidx;
  const int* colp = eidx + E;
  float* out = (float*)d_out;

  char* ws = (char*)d_ws;
  size_t off = 0;
  auto alloc = [&](size_t bytes) -> void* {
    void* p = ws + off;
    off += (bytes + 255) & ~(size_t)255;
    return p;
  };
  unsigned int* deg    = (unsigned int*)alloc((size_t)N * 4);
  unsigned int* cursor = (unsigned int*)alloc((size_t)N * 4);
  unsigned int* rowptr = (unsigned int*)alloc((size_t)(N + 1) * 4);
  float*        dis    = (float*)alloc((size_t)N * 4);
  unsigned int* incl   = (unsigned int*)alloc((size_t)N * 4);
  unsigned int* bsum   = (unsigned int*)alloc(1024 * 4);
  unsigned int* boff   = (unsigned int*)alloc(1024 * 4);
  EdgeIW*       iw     = (EdgeIW*)alloc((size_t)E * 8);
  unsigned short* Wf   = (unsigned short*)alloc((size_t)3 * 16384 * 2);
  float*        bbsum  = (float*)alloc((size_t)3 * 64 * 4);
  (void)ws_size;

  hipMemsetAsync(deg, 0, (size_t)N * 4, stream);

  const int blkE = (E + 255) / 256;
  const int blkN = (N + 255) / 256;
  const int nblk = (N + 1023) / 1024;

  k_count<<<blkE, 256, 0, stream>>>(colp, E, deg);
  k_scan1<<<nblk, 1024, 0, stream>>>(deg, incl, bsum, N);
  k_scan2<<<1, 64, 0, stream>>>(bsum, boff, nblk);
  k_scan3<<<blkN, 256, 0, stream>>>(deg, incl, boff, rowptr, cursor, dis, N, E);
  k_fill<<<blkE, 256, 0, stream>>>(row, colp, E, dis, cursor, iw);
  k_init<<<(N * 16 + 255) / 256, 256, 0, stream>>>(ue, ie, out, Nu, N);
  k_prepw<<<192, 256, 0, stream>>>(W1, b1, W2, b2, Wf, bbsum);

  const int nt = (N + 15) / 16;
  for (int l = 0; l < 3; ++l) {
    int pcol = l * 64;
    int lcol = (l + 1) * 64;
    k_layer<<<nt, 128, 0, stream>>>(rowptr, iw, out,
                                    Wf + (size_t)l * 16384, bbsum + (size_t)l * 64,
                                    N, pcol, lcol);
  }
}